// Round 1
// baseline (139.260 us; speedup 1.0000x reference)
//
#include <hip/hip_runtime.h>

// BConv2d: x (32,32,256,256) f32 NCHW, W (32,32,3,3) f32 binarized to +-1,
// 3x3 'same' conv, out / sqrt(288).
//
// Strategy: 9 accumulated GEMMs (one per filter tap) via mfma_f32_16x16x32_bf16.
//   A = sign(W[:, :, dy, dx])  (co x ci = 32x32, +-1 exact in bf16)
//   B = x[ci, pix]             (ci x pix), staged in LDS transposed+swizzled
// Block: one image n, 64x64 spatial tile, all 32 co. 8 waves = 4 rows x 2 co-halves.
// Rolling 8-row LDS window (66 px x 32 ci bf16) walks down 64 rows.

typedef __attribute__((ext_vector_type(8))) short short8;
typedef __attribute__((ext_vector_type(4))) float f32x4;

__device__ __forceinline__ unsigned short f2bf(float f) {
    unsigned int u = __builtin_bit_cast(unsigned int, f);
    u += 0x7FFFu + ((u >> 16) & 1u);   // RNE
    return (unsigned short)(u >> 16);
}

// LDS layout: slot s (row & 7), pixel p (0..65), ci octet u (0..3).
// 16B unit index = s*264 + p*4 + (u ^ ((p>>1)&3))   [swizzle: bank-balanced
// for both 16B staging writes (p varies, u fixed) and 16B fragment reads
// (p = tile+lane&15 varies, u = lane>>4)].
__device__ __forceinline__ int lds_idx(int s, int p, int u) {
    return s * 264 + p * 4 + (u ^ ((p >> 1) & 3));
}

__global__ __launch_bounds__(512, 4)
void bconv2d_kernel(const float* __restrict__ x, const float* __restrict__ wgt,
                    float* __restrict__ out) {
    __shared__ short8 lds[8 * 264];   // 33792 B

    const int tid = threadIdx.x;
    const int gx0 = blockIdx.x * 64;   // x-strip
    const int Y0  = blockIdx.y * 64;   // y-strip
    const int n   = blockIdx.z;        // image

    const int l      = tid & 63;
    const int wv     = tid >> 6;       // wave 0..7
    const int r      = wv & 3;         // output row within 4-row group
    const int ch     = wv >> 2;        // co half 0..1
    const int lane15 = l & 15;
    const int lhi    = l >> 4;         // 0..3

    // ---- A fragments: sign(W) for all 9 taps, this wave's co-half ----
    // A-frag layout (verified 16x16x32 mapping): lane holds A[row=l&15][k=(l>>4)*8+j]
    short8 afrag[3][3];
    {
        const int co  = ch * 16 + lane15;
        const int ci0 = lhi * 8;
        #pragma unroll
        for (int dy = 0; dy < 3; ++dy) {
            #pragma unroll
            for (int dx = 0; dx < 3; ++dx) {
                short8 a;
                #pragma unroll
                for (int j = 0; j < 8; ++j) {
                    float wval = wgt[((co * 32 + (ci0 + j)) * 3 + dy) * 3 + dx];
                    a[j] = (short)((wval > 0.0f) ? 0x3F80 : 0xBF80);  // +1 / -1 bf16
                }
                afrag[dy][dx] = a;
            }
        }
    }

    // ---- staging: rows [gy0, gy0+nrows) -> LDS (transpose NCHW -> [pix][ci] bf16)
    auto stage = [&](int gy0v, int nrows) {
        const int ntask = nrows * 264;           // 264 = 66 px * 4 ci-octets
        for (int task = tid; task < ntask; task += 512) {
            const int row = task / 264;
            const int rem = task - row * 264;
            const int u   = rem / 66;
            const int p   = rem - u * 66;
            const int gy  = gy0v + row;
            const int gx  = gx0 - 1 + p;
            short8 v = (short8)0;
            if ((unsigned)gy < 256u && (unsigned)gx < 256u) {
                const float* src = x + (((size_t)n * 32 + u * 8) * 256 + gy) * 256 + gx;
                #pragma unroll
                for (int j = 0; j < 8; ++j)
                    v[j] = (short)f2bf(src[(size_t)j * 65536]);
            }
            lds[lds_idx(gy & 7, p, u)] = v;
        }
    };

    stage(Y0 - 1, 6);    // rows Y0-1 .. Y0+4
    __syncthreads();

    const float invdiv = 0.05892556509887896f;   // 1/sqrt(288)

    for (int i = 0; i < 16; ++i) {
        const int Y = Y0 + 4 * i;
        const int y = Y + r;

        f32x4 acc[4];
        #pragma unroll
        for (int tp = 0; tp < 4; ++tp) acc[tp] = (f32x4)0.0f;

        #pragma unroll
        for (int dy = 0; dy < 3; ++dy) {
            const int sbase = ((y - 1 + dy) & 7) * 264;
            #pragma unroll
            for (int dx = 0; dx < 3; ++dx) {
                #pragma unroll
                for (int tp = 0; tp < 4; ++tp) {
                    const int p = tp * 16 + lane15 + dx;
                    short8 b = lds[sbase + p * 4 + (lhi ^ ((p >> 1) & 3))];
                    acc[tp] = __builtin_amdgcn_mfma_f32_16x16x32_bf16(
                        afrag[dy][dx], b, acc[tp], 0, 0, 0);
                }
            }
        }

        // D layout: lane l reg rr -> row(co_local) = (l>>4)*4+rr, col(pix) = l&15
        #pragma unroll
        for (int tp = 0; tp < 4; ++tp) {
            #pragma unroll
            for (int rr = 0; rr < 4; ++rr) {
                const int co = ch * 16 + lhi * 4 + rr;
                out[(((size_t)n * 32 + co) * 256 + y) * 256 + gx0 + tp * 16 + lane15]
                    = acc[tp][rr] * invdiv;
            }
        }

        __syncthreads();              // readers done before overwriting slots
        if (i < 15) stage(Y + 5, 4);  // next 4 rows (slots of Y-3..Y, retired)
        __syncthreads();
    }
}

extern "C" void kernel_launch(void* const* d_in, const int* in_sizes, int n_in,
                              void* d_out, int out_size, void* d_ws, size_t ws_size,
                              hipStream_t stream) {
    const float* x   = (const float*)d_in[0];
    const float* wgt = (const float*)d_in[1];
    float* out = (float*)d_out;
    dim3 grid(4, 4, 32);    // x-strips, y-strips, images
    dim3 block(512);
    bconv2d_kernel<<<grid, block, 0, stream>>>(x, wgt, out);
}